// Round 17
// baseline (679.330 us; speedup 1.0000x reference)
//
#include <hip/hip_runtime.h>
#include <hip/hip_bf16.h>

#define MODEL 2048
#define NHEAD 16
#define HDIM  128
#define BB    2
#define LL    2048
#define N1    (3*MODEL)      // 6144
#define MTOT  (BB*LL)        // 4096

typedef __hip_bfloat16 bf16;
typedef __attribute__((ext_vector_type(8))) short bf16x8;
typedef __attribute__((ext_vector_type(4))) float f32x4;

static __device__ __forceinline__ f32x4 mfma16(bf16x8 a, bf16x8 b, f32x4 c) {
  return __builtin_amdgcn_mfma_f32_16x16x32_bf16(a, b, c, 0, 0, 0);
}

// async global->LDS DMA, 16B per lane; LDS base wave-uniform, dest linear
static __device__ __forceinline__ void gl_lds16(const void* g, void* l) {
  __builtin_amdgcn_global_load_lds(
      (const __attribute__((address_space(1))) unsigned int*)g,
      (__attribute__((address_space(3))) unsigned int*)l, 16, 0, 0);
}

static __device__ __forceinline__ unsigned bfu(float x) {
  bf16 b = __float2bfloat16(x);
  return (unsigned)*reinterpret_cast<unsigned short*>(&b);
}

#define BARRIER __builtin_amdgcn_s_barrier()
#define SCHED0  __builtin_amdgcn_sched_barrier(0)
#define PRIO1 __builtin_amdgcn_s_setprio(1)
#define PRIO0 __builtin_amdgcn_s_setprio(0)

// ---------------- prep: f32 -> bf16 (vectorized x4) ----------------
__global__ void k_cvt(const float* __restrict__ in, bf16* __restrict__ out, int n4) {
  int i = blockIdx.x * blockDim.x + threadIdx.x;
  if (i < n4) {
    float4 v = ((const float4*)in)[i];
    bf16* o = out + (size_t)i * 4;
    o[0] = __float2bfloat16(v.x);
    o[1] = __float2bfloat16(v.y);
    o[2] = __float2bfloat16(v.z);
    o[3] = __float2bfloat16(v.w);
  }
}

// ---------------- prep: transpose f32 [R][C] -> bf16 [C][R] ----------------
__global__ __launch_bounds__(256)
void k_transpose(const float* __restrict__ in, bf16* __restrict__ out, int R, int C) {
  __shared__ float t[32][33];
  const int c0 = blockIdx.x * 32, r0 = blockIdx.y * 32;
  const int tx = threadIdx.x & 31;
  const int ty = threadIdx.x >> 5;   // 0..7
#pragma unroll
  for (int i = 0; i < 4; ++i)
    t[ty + 8*i][tx] = in[(size_t)(r0 + ty + 8*i) * C + c0 + tx];
  __syncthreads();
#pragma unroll
  for (int i = 0; i < 4; ++i)
    out[(size_t)(c0 + ty + 8*i) * R + r0 + tx] = __float2bfloat16(t[tx][ty + 8*i]);
}

// ====== 128x128 GEMM, BK=32, 4 waves, 2-buffer, 5 blocks/CU (r17) ======
// Combines the two individually-verified configs:
//  - r10's 4-wave geometry (wave grid 2Mx2N, 64x64/wave): 8 ds_read_b128 per
//    16 MFMA (ratio 2.0 vs 1.33) -> LDS pipe 384cy ~= MFMA 310cy per
//    block-tile (balanced). r10 failed ONLY on occupancy (2 blocks/CU).
//  - 2 LDS buffers (32KB) -> 5 blocks/CU = 20 waves/CU (r10 had 8).
//  - r15's depth-1 sync (verified correct): stage(t+1)->buf^1 issued at tile
//    t start (buf^1 last read at t-1, barrier crossed); vmcnt(0) at tile end
//    completes it; collective barrier publishes (r8 lesson: staging is
//    distributed across waves).
//  - r6 slot swizzle (0-conflict verified), r12 square XCD chunking.
// EPI==1: RoPE + scatter Q/K row-major + V^T ; EPI==2: bias + f32 out.
template<int EPI>
__global__ __launch_bounds__(256, 5)
void k_gemmP(const bf16* __restrict__ A, const bf16* __restrict__ BT,
             int M, int N, int K,
             float* __restrict__ Cout, const float* __restrict__ bias,
             bf16* __restrict__ Qb, bf16* __restrict__ Kb, bf16* __restrict__ VTb,
             const float* __restrict__ cosT, const float* __restrict__ sinT)
{
  extern __shared__ char smem[];       // 32768 B: buf b @ b*16384 (A @0, B @8192)

  const int tid = threadIdx.x;
  const int wid = tid >> 6, lane = tid & 63;
  const int wm = wid >> 1, wn = wid & 1;       // wave grid 2(M) x 2(N)
  const int lr = lane & 15, lkg = lane >> 4;

  // XCD chunk map (bid%8 = XCD): XCD=(mquarter, nhalf) owns an
  // 8 m-tile x (nbx/2) n-tile chunk, m-inner traversal (A panel L2-fits).
  const int nbx = N >> 7;
  const int xcd = blockIdx.x & 7;
  const int i   = blockIdx.x >> 3;
  const int m0 = (((xcd >> 1) << 3) + (i & 7)) << 7;
  const int n0 = ((xcd & 1) * (nbx >> 1) + (i >> 3)) << 7;

  // staging (r10-verified): wave wid owns rows [wid*32, wid*32+32);
  // source slot carries inverse swizzle, LDS dest linear
  const int scol = ((lane & 3) ^ ((lane >> 3) & 3)) * 8;   // bf16 elems
  const bf16* Asrc = A  + (size_t)(m0 + wid*32 + (lane >> 2)) * K + scol;
  const bf16* Bsrc = BT + (size_t)(n0 + wid*32 + (lane >> 2)) * K + scol;

  auto stage = [&](int t) {
    const bf16* ga = Asrc + t*32;
    const bf16* gb = Bsrc + t*32;
    char* da = smem + (t & 1)*16384 + wid*2048;
    char* db = smem + (t & 1)*16384 + 8192 + wid*2048;
    gl_lds16(ga,                da);
    gl_lds16(ga + (size_t)16*K, da + 1024);
    gl_lds16(gb,                db);
    gl_lds16(gb + (size_t)16*K, db + 1024);
  };

  // ds_read fragment bases (r10/r6-verified): row = 64B, slot XOR-swizzled
  const int slotX = (lkg ^ ((lr >> 1) & 3)) * 16;
  const int aBase = wm*4096 + lr*64 + slotX;          // rows wm*64 + mf*16 + lr
  const int bBase = 8192 + wn*4096 + lr*64 + slotX;   // rows wn*64 + nf*16 + lr

  const f32x4 vzero = {0.f, 0.f, 0.f, 0.f};
  f32x4 acc[4][4];
#pragma unroll
  for (int ii = 0; ii < 4; ++ii)
#pragma unroll
    for (int j = 0; j < 4; ++j) acc[ii][j] = vzero;

  const int nt = K >> 5;               // K-tiles of 32

  // prologue: stage tile 0 -> complete -> publish
  stage(0);
  asm volatile("s_waitcnt vmcnt(0)" ::: "memory");
  SCHED0; BARRIER;

  for (int t = 0; t < nt; ++t) {
    const int buf = (t & 1) * 16384;
    bf16x8 aFr[4], bFr[4];

    // issue next-tile staging first (latency starts earliest)
    if (t + 1 < nt) stage(t + 1);

    // 8 ds_reads (4 A + 4 B)
#pragma unroll
    for (int mf = 0; mf < 4; ++mf)
      aFr[mf] = *(const bf16x8*)(smem + buf + aBase + mf*1024);
#pragma unroll
    for (int nf = 0; nf < 4; ++nf)
      bFr[nf] = *(const bf16x8*)(smem + buf + bBase + nf*1024);

    PRIO1;
#pragma unroll
    for (int mf = 0; mf < 4; ++mf)
#pragma unroll
      for (int nf = 0; nf < 4; ++nf)
        acc[mf][nf] = mfma16(aFr[mf], bFr[nf], acc[mf][nf]);
    PRIO0;
    // stage(t+1) complete before any wave reads buf^1 at t+1
    asm volatile("s_waitcnt vmcnt(0)" ::: "memory");
    SCHED0;
    BARRIER;                          // collective: tile t+1 visible to all
  }

  if constexpr (EPI == 1) {
    const float inv_sqrt_d = 0.08838834764831845f;  // 1/sqrt(128)
#pragma unroll
    for (int nf = 0; nf < 4; ++nf) {
      const int gcb = n0 + wn*64 + nf*16;           // wave-uniform, mult of 16
      const int section = gcb >> 11;                // 0=q 1=k 2=v
      const int cc = (gcb & 2047) + lr;
      const int h = cc >> 7, d = cc & 127;
#pragma unroll
      for (int mf = 0; mf < 4; ++mf) {
#pragma unroll
        for (int reg = 0; reg < 4; ++reg) {
          const int grow = m0 + wm*64 + mf*16 + lkg*4 + reg;
          const int bidx = grow >> 11, lseq = grow & 2047;
          float val = acc[mf][nf][reg];
          if (section < 2) {
            float p = __shfl_xor(val, 1);           // RoPE pair partner
            const int fi = d >> 1;
            float cv = cosT[(size_t)lseq * 64 + fi];
            float sv = sinT[(size_t)lseq * 64 + fi];
            float r = (d & 1) ? fmaf(p, sv, val * cv)
                              : fmaf(val, cv, -p * sv);
            if (section == 0) {
              r *= inv_sqrt_d;
              Qb[((size_t)(bidx*NHEAD + h) * LL + lseq) * HDIM + d] = __float2bfloat16(r);
            } else {
              Kb[((size_t)(bidx*NHEAD + h) * LL + lseq) * HDIM + d] = __float2bfloat16(r);
            }
          } else {
            VTb[((size_t)(bidx*NHEAD + h) * HDIM + d) * LL + lseq] = __float2bfloat16(val);
          }
        }
      }
    }
  } else {
#pragma unroll
    for (int nf = 0; nf < 4; ++nf) {
      const int gcol = n0 + wn*64 + nf*16 + lr;
      const float bv = bias[gcol];
#pragma unroll
      for (int mf = 0; mf < 4; ++mf) {
#pragma unroll
        for (int reg = 0; reg < 4; ++reg) {
          const int grow = m0 + wm*64 + mf*16 + lkg*4 + reg;
          Cout[(size_t)grow * N + gcol] = acc[mf][nf][reg] + bv;
        }
      }
    }
  }
}

// ---------------- flash attention (r14-exact): swapped QK^T ----------------
// s2 = mfma(K,Q): lane (lr,lkg) holds S[q=lr][kv=c*16+lkg*4+reg] -> row
// softmax is 16 lane-local values + 2 shfl. P packs 4 bf16 -> b64 writes.
// Balanced q-tile pairing (r9): block bx does (15-bx) then bx.
__global__ __launch_bounds__(256, 2)
void k_attn(const bf16* __restrict__ Qb, const bf16* __restrict__ Kb,
            const bf16* __restrict__ VTb, bf16* __restrict__ attnA)
{
  __shared__ bf16 Ks[64][136];
  __shared__ bf16 Vs[128][72];
  __shared__ bf16 Ps[4][32][72];

  const int bh  = blockIdx.y;
  const int bx  = blockIdx.x;                 // 0..7
  const int tid = threadIdx.x;
  const int wid = tid >> 6, lane = tid & 63;
  const int lr  = lane & 15, lkg = lane >> 4;

  const bf16* Qh = Qb  + (size_t)bh * LL * HDIM;
  const bf16* Kh = Kb  + (size_t)bh * LL * HDIM;
  const bf16* Vh = VTb + (size_t)bh * HDIM * LL;
  const int b = bh >> 4, h = bh & 15;
  const f32x4 vzero = {0.f, 0.f, 0.f, 0.f};

  for (int pp = 0; pp < 2; ++pp) {
    const int qt  = pp ? bx : (15 - bx);      // heavy tile first
    const int Q0  = qt * 128;
    const int q0w = Q0 + wid * 32;

    bf16x8 qf[2][4];
#pragma unroll
    for (int qr = 0; qr < 2; ++qr)
#pragma unroll
      for (int kk = 0; kk < 4; ++kk)
        qf[qr][kk] = *(const bf16x8*)(Qh + (size_t)(q0w + qr*16 + lr) * HDIM + kk*32 + lkg*8);

    f32x4 oacc[2][8];
#pragma unroll
    for (int qr = 0; qr < 2; ++qr)
#pragma unroll
      for (int db = 0; db < 8; ++db) oacc[qr][db] = vzero;
    float ml[2] = {-INFINITY, -INFINITY};
    float ll[2] = {0.f, 0.f};

    const int NT = Q0 / 64 + 2;
    bf16x8 kpre[4], vpre[4];
#pragma unroll
    for (int j = 0; j < 4; ++j) {
      const int c = j*256 + tid;
      kpre[j] = *(const bf16x8*)(Kh + (size_t)(c >> 4) * HDIM + (c & 15) * 8);
      vpre[j] = *(const bf16x8*)(Vh + (size_t)(c >> 3) * LL + (c & 7) * 8);
    }

    for (int kt = 0; kt < NT; ++kt) {
      const int kbase = kt * 64;
      __syncthreads();
#pragma unroll
      for (int j = 0; j < 4; ++j) {
        const int c = j*256 + tid;
        *(bf16x8*)&Ks[c >> 4][(c & 15) * 8] = kpre[j];
        *(bf16x8*)&Vs[c >> 3][(c & 7) * 8]  = vpre[j];
      }
      __syncthreads();
      if (kt + 1 < NT) {
#pragma unroll
        for (int j = 0; j < 4; ++j) {
          const int c = j*256 + tid;
          kpre[j] = *(const bf16x8*)(Kh + (size_t)((kt+1)*64 + (c >> 4)) * HDIM + (c & 15) * 8);
          vpre[j] = *(const bf16x8*)(Vh + (size_t)(c >> 3) * LL + (kt+1)*64 + (c & 7) * 8);
        }
      }
      if (kbase <= q0w + 31) {
        f32x4 s2[2][4];
#pragma unroll
        for (int qr = 0; qr < 2; ++qr)
#pragma unroll
          for (int c = 0; c < 4; ++c) s2[qr][c] = vzero;
#pragma unroll
        for (int c = 0; c < 4; ++c) {
          bf16x8 kf[4];
#pragma unroll
          for (int kk = 0; kk < 4; ++kk)
            kf[kk] = *(const bf16x8*)&Ks[c*16 + lr][kk*32 + lkg*8];
#pragma unroll
          for (int qr = 0; qr < 2; ++qr)
#pragma unroll
            for (int kk = 0; kk < 4; ++kk)
              s2[qr][c] = mfma16(kf[kk], qf[qr][kk], s2[qr][c]);
        }
#pragma unroll
        for (int qr = 0; qr < 2; ++qr) {
          const int qrow = q0w + qr*16 + lr;
          float pv[4][4];
#pragma unroll
          for (int c = 0; c < 4; ++c)
#pragma unroll
            for (int reg = 0; reg < 4; ++reg) {
              const int kv = kbase + c*16 + lkg*4 + reg;
              pv[c][reg] = (kv <= qrow) ? s2[qr][c][reg] : -INFINITY;
            }
          float tm = pv[0][0];
#pragma unroll
          for (int c = 0; c < 4; ++c)
#pragma unroll
            for (int reg = 0; reg < 4; ++reg)
              if (c || reg) tm = fmaxf(tm, pv[c][reg]);
          tm = fmaxf(tm, __shfl_xor(tm, 16));
          tm = fmaxf(tm, __shfl_xor(tm, 32));
          const float mnew = fmaxf(ml[qr], tm);
          const float scl  = __expf(ml[qr] - mnew);
          ml[qr] = mnew;
          float rs = 0.f;
#pragma unroll
          for (int c = 0; c < 4; ++c)
#pragma unroll
            for (int reg = 0; reg < 4; ++reg) {
              pv[c][reg] = __expf(pv[c][reg] - mnew);
              rs += pv[c][reg];
            }
          rs += __shfl_xor(rs, 16);
          rs += __shfl_xor(rs, 32);
          ll[qr] = ll[qr] * scl + rs;
#pragma unroll
          for (int c = 0; c < 4; ++c) {
            unsigned lo = bfu(pv[c][0]) | (bfu(pv[c][1]) << 16);
            unsigned hi = bfu(pv[c][2]) | (bfu(pv[c][3]) << 16);
            *(uint2*)&Ps[wid][qr*16 + lr][c*16 + lkg*4] = make_uint2(lo, hi);
          }
          float sr[4];
#pragma unroll
          for (int reg = 0; reg < 4; ++reg) sr[reg] = __shfl(scl, lkg*4 + reg);
#pragma unroll
          for (int db = 0; db < 8; ++db) {
            oacc[qr][db][0] *= sr[0]; oacc[qr][db][1] *= sr[1];
            oacc[qr][db][2] *= sr[2]; oacc[qr][db][3] *= sr[3];
          }
        }
        asm volatile("s_waitcnt lgkmcnt(0)" ::: "memory");
        __builtin_amdgcn_sched_barrier(0);
        bf16x8 pf[2][2];
#pragma unroll
        for (int qr = 0; qr < 2; ++qr)
#pragma unroll
          for (int k2 = 0; k2 < 2; ++k2)
            pf[qr][k2] = *(const bf16x8*)&Ps[wid][qr*16 + lr][k2*32 + lkg*8];
#pragma unroll
        for (int db = 0; db < 8; ++db) {
          bf16x8 vf0 = *(const bf16x8*)&Vs[db*16 + lr][lkg*8];
          bf16x8 vf1 = *(const bf16x8*)&Vs[db*16 + lr][32 + lkg*8];
#pragma unroll
          for (int qr = 0; qr < 2; ++qr) {
            oacc[qr][db] = mfma16(pf[qr][0], vf0, oacc[qr][db]);
            oacc[qr][db] = mfma16(pf[qr][1], vf1, oacc[qr][db]);
          }
        }
      }
    }

#pragma unroll
    for (int qr = 0; qr < 2; ++qr) {
      const float myinv = 1.0f / ll[qr];
      float li[4];
#pragma unroll
      for (int reg = 0; reg < 4; ++reg) li[reg] = __shfl(myinv, lkg*4 + reg);
#pragma unroll
      for (int reg = 0; reg < 4; ++reg) {
        const int row = q0w + qr*16 + lkg*4 + reg;
        bf16* dst = attnA + ((size_t)(b*LL + row)) * MODEL + h * HDIM;
#pragma unroll
        for (int db = 0; db < 8; ++db)
          dst[db*16 + lr] = __float2bfloat16(oacc[qr][db][reg] * li[reg]);
      }
    }
  }
}

// ---------------- launch ----------------
extern "C" void kernel_launch(void* const* d_in, const int* in_sizes, int n_in,
                              void* d_out, int out_size, void* d_ws, size_t ws_size,
                              hipStream_t stream)
{
  const float* x    = (const float*)d_in[0];
  const float* cosT = (const float*)d_in[1];
  const float* sinT = (const float*)d_in[2];
  const float* Wqkv = (const float*)d_in[3];
  const float* Wc   = (const float*)d_in[4];
  const float* bc   = (const float*)d_in[5];
  float* out = (float*)d_out;

  // workspace layout (bytes):
  //   x16    @ 0         : 16,777,216   (reused as attnA later)
  //   WqkvT  @ 16777216  : 25,165,824
  //   WcT    @ 41943040  :  8,388,608
  //   Qb     @ 50331648  : 16,777,216
  //   Kb     @ 67108864  : 16,777,216
  //   VTb    @ 83886080  : 16,777,216   -> total 100,663,296 B
  if (ws_size < 100663296u) return;
  char* w = (char*)d_ws;
  bf16* x16   = (bf16*)(w);
  bf16* WqkvT = (bf16*)(w + (size_t)16777216);
  bf16* WcT   = (bf16*)(w + (size_t)41943040);
  bf16* Qb    = (bf16*)(w + (size_t)50331648);
  bf16* Kb    = (bf16*)(w + (size_t)67108864);
  bf16* VTb   = (bf16*)(w + (size_t)83886080);
  bf16* attnA = x16;   // overlay: x16 dead after GEMM1

  // allow 32KB dynamic LDS (idempotent; not a stream op -> capture-safe)
  hipFuncSetAttribute(reinterpret_cast<const void*>(&k_gemmP<1>),
                      hipFuncAttributeMaxDynamicSharedMemorySize, 32768);
  hipFuncSetAttribute(reinterpret_cast<const void*>(&k_gemmP<2>),
                      hipFuncAttributeMaxDynamicSharedMemorySize, 32768);

  k_cvt<<<(MTOT*MODEL/4 + 255)/256, 256, 0, stream>>>(x, x16, MTOT*MODEL/4);
  k_transpose<<<dim3(N1/32,    MODEL/32), 256, 0, stream>>>(Wqkv, WqkvT, MODEL, N1);
  k_transpose<<<dim3(MODEL/32, MODEL/32), 256, 0, stream>>>(Wc,   WcT,   MODEL, MODEL);

  // grid 48*32 = 1536 blocks (5 blocks/CU -> ~1.2 rounds)
  k_gemmP<1><<<(N1/128)*(MTOT/128), 256, 32768, stream>>>(
      x16, WqkvT, MTOT, N1, MODEL,
      nullptr, nullptr, Qb, Kb, VTb, cosT, sinT);

  // grid 8*32 = 256 blocks, uniform 17 tile-units each
  k_attn<<<dim3(8, BB*NHEAD), 256, 0, stream>>>(Qb, Kb, VTb, attnA);

  // grid 16*32 = 512 blocks
  k_gemmP<2><<<(MODEL/128)*(MTOT/128), 256, 32768, stream>>>(
      attnA, WcT, MTOT, MODEL, MODEL,
      out, bc, nullptr, nullptr, nullptr, nullptr, nullptr);
}

// Round 18
// 302.117 us; speedup vs baseline: 2.2486x; 2.2486x over previous
//
#include <hip/hip_runtime.h>
#include <hip/hip_bf16.h>

#define MODEL 2048
#define NHEAD 16
#define HDIM  128
#define BB    2
#define LL    2048
#define N1    (3*MODEL)      // 6144
#define MTOT  (BB*LL)        // 4096

typedef __hip_bfloat16 bf16;
typedef __attribute__((ext_vector_type(8))) short bf16x8;
typedef __attribute__((ext_vector_type(4))) float f32x4;

static __device__ __forceinline__ f32x4 mfma16(bf16x8 a, bf16x8 b, f32x4 c) {
  return __builtin_amdgcn_mfma_f32_16x16x32_bf16(a, b, c, 0, 0, 0);
}

// async global->LDS DMA, 16B per lane; LDS base wave-uniform, dest linear
static __device__ __forceinline__ void gl_lds16(const void* g, void* l) {
  __builtin_amdgcn_global_load_lds(
      (const __attribute__((address_space(1))) unsigned int*)g,
      (__attribute__((address_space(3))) unsigned int*)l, 16, 0, 0);
}

static __device__ __forceinline__ unsigned short bfraw(float x) {
  bf16 b = __float2bfloat16(x);
  return *reinterpret_cast<unsigned short*>(&b);
}
static __device__ __forceinline__ unsigned bfu(float x) {
  return (unsigned)bfraw(x);
}

#define BARRIER __builtin_amdgcn_s_barrier()
#define SCHED0  __builtin_amdgcn_sched_barrier(0)
#define PRIO1 __builtin_amdgcn_s_setprio(1)
#define PRIO0 __builtin_amdgcn_s_setprio(0)

// ---------------- prep: transpose f32 [R][C] -> bf16 [C][R] ----------------
__global__ __launch_bounds__(256)
void k_transpose(const float* __restrict__ in, bf16* __restrict__ out, int R, int C) {
  __shared__ float t[32][33];
  const int c0 = blockIdx.x * 32, r0 = blockIdx.y * 32;
  const int tx = threadIdx.x & 31;
  const int ty = threadIdx.x >> 5;   // 0..7
#pragma unroll
  for (int i = 0; i < 4; ++i)
    t[ty + 8*i][tx] = in[(size_t)(r0 + ty + 8*i) * C + c0 + tx];
  __syncthreads();
#pragma unroll
  for (int i = 0; i < 4; ++i)
    out[(size_t)(c0 + ty + 8*i) * R + r0 + tx] = __float2bfloat16(t[tx][ty + 8*i]);
}

// ====== 128x128 GEMM, BK=32, 3-buffer, 3 blocks/CU (r18) ======
// r12/r16-proven skeleton: 8 waves 2Mx4N, lockstep tile, distributed staging
// + collective barrier per tile [r8], mod-3 rotation, depth-2 staging [r12
// safety], slot swizzle [r6, 0-conflict], per-XCD L2-fit chunking [r12].
// r18 (EPI==1): A is f32 (the raw x input) -- conversion FUSED into staging:
// per wave/tile 2 global_load_dwordx4(f32) + cvt + 1 ds_write_b128 directly
// to the swizzled slot  row*64 + ((lane&3)^((lane>>3)&3))*16  (algebraically
// identical layout to the gl_lds + source-permutation path: phys_slot =
// s_log ^ ((row>>1)&3) in both). k_cvt kernel eliminated.
// Schedule/tile t: ds_read frags(t); writeA(t+2) from regs(loaded t-1);
// stageB(t+2); loadAf32(t+3); MFMAs; vmcnt(3) [completes B(t+1),A(t+2)f32];
// lgkm0 [publish ds_writes]; barrier. A-chunk = m-octant (512 rows f32 =
// 4MB, L2-fit), B full-width streamed (re-read hits L2, m-inner x4).
// EPI==2: A bf16, gl_lds staging + quarter-chunking (r16-exact).
template<int EPI>
__global__ __launch_bounds__(512, 4)
void k_gemmP(const void* __restrict__ Ain, const bf16* __restrict__ BT,
             int M, int N, int K,
             float* __restrict__ Cout, const float* __restrict__ bias,
             bf16* __restrict__ Qb, bf16* __restrict__ Kb, bf16* __restrict__ VTb,
             const float* __restrict__ cosT, const float* __restrict__ sinT)
{
  constexpr int ABUF = 8192;           // one A tile (128 rows x 64B bf16)
  constexpr int BBUF = 8192;
  constexpr int AREG = 3 * ABUF;       // 24576
  extern __shared__ char smem[];       // 49152 B

  const int tid = threadIdx.x;
  const int wid = tid >> 6, lane = tid & 63;
  const int wm = wid >> 2, wn = wid & 3;       // wave grid 2(M) x 4(N)
  const int lr = lane & 15, lkg = lane >> 4;

  // XCD chunk map (bid%8 = XCD)
  const int nbx = N >> 7;
  const int xcd = blockIdx.x & 7;
  const int i   = blockIdx.x >> 3;
  int m0, n0;
  if constexpr (EPI == 1) {
    // m-octant (4 m-tiles = 512 rows f32 = 4MB, L2-fit), all n, m-inner
    m0 = ((xcd << 2) + (i & 3)) << 7;
    n0 = (i >> 2) << 7;
  } else {
    m0 = (((xcd >> 1) << 3) + (i & 7)) << 7;
    n0 = ((xcd & 1) * (nbx >> 1) + (i >> 3)) << 7;
  }

  // B staging: wave wid owns 16 rows; source slot carries inverse swizzle
  const int scol = ((lane & 3) ^ ((lane >> 3) & 3)) * 8;   // bf16 elems
  const bf16* Bsrc = BT + (size_t)(n0 + wid*16 + (lane >> 2)) * K + scol;
  auto stageB = [&](int t) {
    gl_lds16(Bsrc + t*32, smem + AREG + (t % 3)*BBUF + wid*1024);
  };

  // A path
  const bf16*  AsrcH = (const bf16*)Ain;
  const float* AsrcF = (const float*)Ain;
  const bf16*  AsrcB = AsrcH + (size_t)(m0 + wid*16 + (lane >> 2)) * K + scol;
  const float* AsrcX = AsrcF + (size_t)(m0 + wid*16 + (lane >> 2)) * K + (lane & 3) * 8;
  const int awAddr = (wid*16 + (lane >> 2)) * 64 + ((lane & 3) ^ ((lane >> 3) & 3)) * 16;

  float4 rA0, rA1;                     // f32 A data for the pending tile
  auto loadAf = [&](int t) {
    rA0 = *(const float4*)(AsrcX + (size_t)t * 32);
    rA1 = *(const float4*)(AsrcX + (size_t)t * 32 + 4);
  };
  auto writeA = [&](int tbuf) {        // cvt regs -> swizzled ds_write_b128
    union { bf16x8 v; unsigned short s[8]; } u;
    u.s[0] = bfraw(rA0.x); u.s[1] = bfraw(rA0.y);
    u.s[2] = bfraw(rA0.z); u.s[3] = bfraw(rA0.w);
    u.s[4] = bfraw(rA1.x); u.s[5] = bfraw(rA1.y);
    u.s[6] = bfraw(rA1.z); u.s[7] = bfraw(rA1.w);
    *(bf16x8*)(smem + (tbuf % 3)*ABUF + awAddr) = u.v;
  };
  auto stageA_bf = [&](int t) {
    gl_lds16(AsrcB + t*32, smem + (t % 3)*ABUF + wid*1024);
  };

  // ds_read fragment bases (row = 64B, slot XOR-swizzled by row bits 1-2)
  const int slotX = (lkg ^ ((lr >> 1) & 3)) * 16;
  const int aBase = wm*4096 + lr*64 + slotX;
  const int bBase = wn*2048 + lr*64 + slotX;

  const f32x4 vzero = {0.f, 0.f, 0.f, 0.f};
  f32x4 acc[4][2];
#pragma unroll
  for (int ii = 0; ii < 4; ++ii)
#pragma unroll
    for (int j = 0; j < 2; ++j) acc[ii][j] = vzero;

  const int nt = K >> 5;              // K-tiles of 32 (= 64 here)

  // prologue
  if constexpr (EPI == 1) {
    loadAf(0);
    stageB(0); stageB(1);
    writeA(0);                         // compiler auto-waits rA use
    loadAf(1);
    writeA(1);
    loadAf(2);
    asm volatile("s_waitcnt vmcnt(3) lgkmcnt(0)" ::: "memory");  // B0 done
  } else {
    stageA_bf(0); stageB(0); stageA_bf(1); stageB(1);
    asm volatile("s_waitcnt vmcnt(2)" ::: "memory");
  }
  SCHED0; BARRIER;

  for (int t = 0; t < nt; ++t) {
    const int bufA = (t % 3) * ABUF;
    const int bufB = AREG + (t % 3) * BBUF;
    const int t2 = (t + 2 < nt) ? t + 2 : nt - 1;   // clamp: dead-buffer dup
    bf16x8 aFr[4], bFr[2];

#pragma unroll
    for (int mf = 0; mf < 4; ++mf)
      aFr[mf] = *(const bf16x8*)(smem + bufA + aBase + mf*1024);
#pragma unroll
    for (int nf = 0; nf < 2; ++nf)
      bFr[nf] = *(const bf16x8*)(smem + bufB + bBase + nf*1024);

    if constexpr (EPI == 1) {
      writeA(t + 2);                   // data loaded at t-1 (tile t2 data)
      stageB(t2);
      const int t3 = (t + 3 < nt) ? t + 3 : nt - 1;
      loadAf(t3);
    } else {
      stageA_bf(t2); stageB(t2);
    }

    PRIO1;
#pragma unroll
    for (int mf = 0; mf < 4; ++mf)
#pragma unroll
      for (int nf = 0; nf < 2; ++nf)
        acc[mf][nf] = mfma16(aFr[mf], bFr[nf], acc[mf][nf]);
    PRIO0;
    if constexpr (EPI == 1) {
      // outstanding: B(t+2)[1] + Af32(t+3)[2]; completes B(t+1), A(t+2)f32
      asm volatile("s_waitcnt vmcnt(3) lgkmcnt(0)" ::: "memory");
    } else {
      asm volatile("s_waitcnt vmcnt(2)" ::: "memory");
    }
    SCHED0;
    BARRIER;                          // collective: tile t+1 visible to all
  }

  if constexpr (EPI == 1) {
    const float inv_sqrt_d = 0.08838834764831845f;  // 1/sqrt(128)
#pragma unroll
    for (int nf = 0; nf < 2; ++nf) {
      const int gcb = n0 + wn*32 + nf*16;           // wave-uniform, mult of 16
      const int section = gcb >> 11;                // 0=q 1=k 2=v
      const int cc = (gcb & 2047) + lr;
      const int h = cc >> 7, d = cc & 127;
#pragma unroll
      for (int mf = 0; mf < 4; ++mf) {
#pragma unroll
        for (int reg = 0; reg < 4; ++reg) {
          const int grow = m0 + wm*64 + mf*16 + lkg*4 + reg;
          const int bidx = grow >> 11, lseq = grow & 2047;
          float val = acc[mf][nf][reg];
          if (section < 2) {
            float p = __shfl_xor(val, 1);           // RoPE pair partner
            const int fi = d >> 1;
            float cv = cosT[(size_t)lseq * 64 + fi];
            float sv = sinT[(size_t)lseq * 64 + fi];
            float r = (d & 1) ? fmaf(p, sv, val * cv)
                              : fmaf(val, cv, -p * sv);
            if (section == 0) {
              r *= inv_sqrt_d;
              Qb[((size_t)(bidx*NHEAD + h) * LL + lseq) * HDIM + d] = __float2bfloat16(r);
            } else {
              Kb[((size_t)(bidx*NHEAD + h) * LL + lseq) * HDIM + d] = __float2bfloat16(r);
            }
          } else {
            VTb[((size_t)(bidx*NHEAD + h) * HDIM + d) * LL + lseq] = __float2bfloat16(val);
          }
        }
      }
    }
  } else {
#pragma unroll
    for (int nf = 0; nf < 2; ++nf) {
      const int gcol = n0 + wn*32 + nf*16 + lr;
      const float bv = bias[gcol];
#pragma unroll
      for (int mf = 0; mf < 4; ++mf) {
#pragma unroll
        for (int reg = 0; reg < 4; ++reg) {
          const int grow = m0 + wm*64 + mf*16 + lkg*4 + reg;
          Cout[(size_t)grow * N + gcol] = acc[mf][nf][reg] + bv;
        }
      }
    }
  }
}

// ---------------- flash attention (r14-exact): swapped QK^T ----------------
// s2 = mfma(K,Q): lane (lr,lkg) holds S[q=lr][kv=c*16+lkg*4+reg] -> row
// softmax is 16 lane-local values + 2 shfl. P packs 4 bf16 -> b64 writes.
// Balanced q-tile pairing (r9): block bx does (15-bx) then bx.
__global__ __launch_bounds__(256, 2)
void k_attn(const bf16* __restrict__ Qb, const bf16* __restrict__ Kb,
            const bf16* __restrict__ VTb, bf16* __restrict__ attnA)
{
  __shared__ bf16 Ks[64][136];
  __shared__ bf16 Vs[128][72];
  __shared__ bf16 Ps[4][32][72];

  const int bh  = blockIdx.y;
  const int bx  = blockIdx.x;                 // 0..7
  const int tid = threadIdx.x;
  const int wid = tid >> 6, lane = tid & 63;
  const int lr  = lane & 15, lkg = lane >> 4;

  const bf16* Qh = Qb  + (size_t)bh * LL * HDIM;
  const bf16* Kh = Kb  + (size_t)bh * LL * HDIM;
  const bf16* Vh = VTb + (size_t)bh * HDIM * LL;
  const int b = bh >> 4, h = bh & 15;
  const f32x4 vzero = {0.f, 0.f, 0.f, 0.f};

  for (int pp = 0; pp < 2; ++pp) {
    const int qt  = pp ? bx : (15 - bx);      // heavy tile first
    const int Q0  = qt * 128;
    const int q0w = Q0 + wid * 32;

    bf16x8 qf[2][4];
#pragma unroll
    for (int qr = 0; qr < 2; ++qr)
#pragma unroll
      for (int kk = 0; kk < 4; ++kk)
        qf[qr][kk] = *(const bf16x8*)(Qh + (size_t)(q0w + qr*16 + lr) * HDIM + kk*32 + lkg*8);

    f32x4 oacc[2][8];
#pragma unroll
    for (int qr = 0; qr < 2; ++qr)
#pragma unroll
      for (int db = 0; db < 8; ++db) oacc[qr][db] = vzero;
    float ml[2] = {-INFINITY, -INFINITY};
    float ll[2] = {0.f, 0.f};

    const int NT = Q0 / 64 + 2;
    bf16x8 kpre[4], vpre[4];
#pragma unroll
    for (int j = 0; j < 4; ++j) {
      const int c = j*256 + tid;
      kpre[j] = *(const bf16x8*)(Kh + (size_t)(c >> 4) * HDIM + (c & 15) * 8);
      vpre[j] = *(const bf16x8*)(Vh + (size_t)(c >> 3) * LL + (c & 7) * 8);
    }

    for (int kt = 0; kt < NT; ++kt) {
      const int kbase = kt * 64;
      __syncthreads();
#pragma unroll
      for (int j = 0; j < 4; ++j) {
        const int c = j*256 + tid;
        *(bf16x8*)&Ks[c >> 4][(c & 15) * 8] = kpre[j];
        *(bf16x8*)&Vs[c >> 3][(c & 7) * 8]  = vpre[j];
      }
      __syncthreads();
      if (kt + 1 < NT) {
#pragma unroll
        for (int j = 0; j < 4; ++j) {
          const int c = j*256 + tid;
          kpre[j] = *(const bf16x8*)(Kh + (size_t)((kt+1)*64 + (c >> 4)) * HDIM + (c & 15) * 8);
          vpre[j] = *(const bf16x8*)(Vh + (size_t)(c >> 3) * LL + (kt+1)*64 + (c & 7) * 8);
        }
      }
      if (kbase <= q0w + 31) {
        f32x4 s2[2][4];
#pragma unroll
        for (int qr = 0; qr < 2; ++qr)
#pragma unroll
          for (int c = 0; c < 4; ++c) s2[qr][c] = vzero;
#pragma unroll
        for (int c = 0; c < 4; ++c) {
          bf16x8 kf[4];
#pragma unroll
          for (int kk = 0; kk < 4; ++kk)
            kf[kk] = *(const bf16x8*)&Ks[c*16 + lr][kk*32 + lkg*8];
#pragma unroll
          for (int qr = 0; qr < 2; ++qr)
#pragma unroll
            for (int kk = 0; kk < 4; ++kk)
              s2[qr][c] = mfma16(kf[kk], qf[qr][kk], s2[qr][c]);
        }
#pragma unroll
        for (int qr = 0; qr < 2; ++qr) {
          const int qrow = q0w + qr*16 + lr;
          float pv[4][4];
#pragma unroll
          for (int c = 0; c < 4; ++c)
#pragma unroll
            for (int reg = 0; reg < 4; ++reg) {
              const int kv = kbase + c*16 + lkg*4 + reg;
              pv[c][reg] = (kv <= qrow) ? s2[qr][c][reg] : -INFINITY;
            }
          float tm = pv[0][0];
#pragma unroll
          for (int c = 0; c < 4; ++c)
#pragma unroll
            for (int reg = 0; reg < 4; ++reg)
              if (c || reg) tm = fmaxf(tm, pv[c][reg]);
          tm = fmaxf(tm, __shfl_xor(tm, 16));
          tm = fmaxf(tm, __shfl_xor(tm, 32));
          const float mnew = fmaxf(ml[qr], tm);
          const float scl  = __expf(ml[qr] - mnew);
          ml[qr] = mnew;
          float rs = 0.f;
#pragma unroll
          for (int c = 0; c < 4; ++c)
#pragma unroll
            for (int reg = 0; reg < 4; ++reg) {
              pv[c][reg] = __expf(pv[c][reg] - mnew);
              rs += pv[c][reg];
            }
          rs += __shfl_xor(rs, 16);
          rs += __shfl_xor(rs, 32);
          ll[qr] = ll[qr] * scl + rs;
#pragma unroll
          for (int c = 0; c < 4; ++c) {
            unsigned lo = bfu(pv[c][0]) | (bfu(pv[c][1]) << 16);
            unsigned hi = bfu(pv[c][2]) | (bfu(pv[c][3]) << 16);
            *(uint2*)&Ps[wid][qr*16 + lr][c*16 + lkg*4] = make_uint2(lo, hi);
          }
          float sr[4];
#pragma unroll
          for (int reg = 0; reg < 4; ++reg) sr[reg] = __shfl(scl, lkg*4 + reg);
#pragma unroll
          for (int db = 0; db < 8; ++db) {
            oacc[qr][db][0] *= sr[0]; oacc[qr][db][1] *= sr[1];
            oacc[qr][db][2] *= sr[2]; oacc[qr][db][3] *= sr[3];
          }
        }
        asm volatile("s_waitcnt lgkmcnt(0)" ::: "memory");
        __builtin_amdgcn_sched_barrier(0);
        bf16x8 pf[2][2];
#pragma unroll
        for (int qr = 0; qr < 2; ++qr)
#pragma unroll
          for (int k2 = 0; k2 < 2; ++k2)
            pf[qr][k2] = *(const bf16x8*)&Ps[wid][qr*16 + lr][k2*32 + lkg*8];
#pragma unroll
        for (int db = 0; db < 8; ++db) {
          bf16x8 vf0 = *(const bf16x8*)&Vs[db*16 + lr][lkg*8];
          bf16x8 vf1 = *(const bf16x8*)&Vs[db*16 + lr][32 + lkg*8];
#pragma unroll
          for (int qr = 0; qr < 2; ++qr) {
            oacc[qr][db] = mfma16(pf[qr][0], vf0, oacc[qr][db]);
            oacc[qr][db] = mfma16(pf[qr][1], vf1, oacc[qr][db]);
          }
        }
      }
    }

#pragma unroll
    for (int qr = 0; qr < 2; ++qr) {
      const float myinv = 1.0f / ll[qr];
      float li[4];
#pragma unroll
      for (int reg = 0; reg < 4; ++reg) li[reg] = __shfl(myinv, lkg*4 + reg);
#pragma unroll
      for (int reg = 0; reg < 4; ++reg) {
        const int row = q0w + qr*16 + lkg*4 + reg;
        bf16* dst = attnA + ((size_t)(b*LL + row)) * MODEL + h * HDIM;
#pragma unroll
        for (int db = 0; db < 8; ++db)
          dst[db*16 + lr] = __float2bfloat16(oacc[qr][db][reg] * li[reg]);
      }
    }
  }
}

// ---------------- launch ----------------
extern "C" void kernel_launch(void* const* d_in, const int* in_sizes, int n_in,
                              void* d_out, int out_size, void* d_ws, size_t ws_size,
                              hipStream_t stream)
{
  const float* x    = (const float*)d_in[0];
  const float* cosT = (const float*)d_in[1];
  const float* sinT = (const float*)d_in[2];
  const float* Wqkv = (const float*)d_in[3];
  const float* Wc   = (const float*)d_in[4];
  const float* bc   = (const float*)d_in[5];
  float* out = (float*)d_out;

  // workspace layout (bytes):
  //   attnA  @ 0         : 16,777,216
  //   WqkvT  @ 16777216  : 25,165,824
  //   WcT    @ 41943040  :  8,388,608
  //   Qb     @ 50331648  : 16,777,216
  //   Kb     @ 67108864  : 16,777,216
  //   VTb    @ 83886080  : 16,777,216   -> total 100,663,296 B
  if (ws_size < 100663296u) return;
  char* w = (char*)d_ws;
  bf16* attnA = (bf16*)(w);
  bf16* WqkvT = (bf16*)(w + (size_t)16777216);
  bf16* WcT   = (bf16*)(w + (size_t)41943040);
  bf16* Qb    = (bf16*)(w + (size_t)50331648);
  bf16* Kb    = (bf16*)(w + (size_t)67108864);
  bf16* VTb   = (bf16*)(w + (size_t)83886080);

  // allow 48KB dynamic LDS (idempotent; not a stream op -> capture-safe)
  hipFuncSetAttribute(reinterpret_cast<const void*>(&k_gemmP<1>),
                      hipFuncAttributeMaxDynamicSharedMemorySize, 49152);
  hipFuncSetAttribute(reinterpret_cast<const void*>(&k_gemmP<2>),
                      hipFuncAttributeMaxDynamicSharedMemorySize, 49152);

  k_transpose<<<dim3(N1/32,    MODEL/32), 256, 0, stream>>>(Wqkv, WqkvT, MODEL, N1);
  k_transpose<<<dim3(MODEL/32, MODEL/32), 256, 0, stream>>>(Wc,   WcT,   MODEL, MODEL);

  // grid 48*32 = 1536 blocks (3 blocks/CU -> 2 exact rounds); A = f32 x, fused cvt
  k_gemmP<1><<<(N1/128)*(MTOT/128), 512, 49152, stream>>>(
      x, WqkvT, MTOT, N1, MODEL,
      nullptr, nullptr, Qb, Kb, VTb, cosT, sinT);

  // grid 8*32 = 256 blocks, uniform 17 tile-units each
  k_attn<<<dim3(8, BB*NHEAD), 256, 0, stream>>>(Qb, Kb, VTb, attnA);

  // grid 16*32 = 512 blocks
  k_gemmP<2><<<(MODEL/128)*(MTOT/128), 512, 49152, stream>>>(
      attnA, WcT, MTOT, MODEL, MODEL,
      out, bc, nullptr, nullptr, nullptr, nullptr, nullptr);
}

// Round 19
// 296.693 us; speedup vs baseline: 2.2897x; 1.0183x over previous
//
#include <hip/hip_runtime.h>
#include <hip/hip_bf16.h>

#define MODEL 2048
#define NHEAD 16
#define HDIM  128
#define BB    2
#define LL    2048
#define N1    (3*MODEL)      // 6144
#define MTOT  (BB*LL)        // 4096

typedef __hip_bfloat16 bf16;
typedef __attribute__((ext_vector_type(8))) short bf16x8;
typedef __attribute__((ext_vector_type(4))) float f32x4;

static __device__ __forceinline__ f32x4 mfma16(bf16x8 a, bf16x8 b, f32x4 c) {
  return __builtin_amdgcn_mfma_f32_16x16x32_bf16(a, b, c, 0, 0, 0);
}

// async global->LDS DMA, 16B per lane; LDS base wave-uniform, dest linear
static __device__ __forceinline__ void gl_lds16(const void* g, void* l) {
  __builtin_amdgcn_global_load_lds(
      (const __attribute__((address_space(1))) unsigned int*)g,
      (__attribute__((address_space(3))) unsigned int*)l, 16, 0, 0);
}

static __device__ __forceinline__ unsigned bfu(float x) {
  bf16 b = __float2bfloat16(x);
  return (unsigned)*reinterpret_cast<unsigned short*>(&b);
}

#define BARRIER __builtin_amdgcn_s_barrier()
#define SCHED0  __builtin_amdgcn_sched_barrier(0)
#define PRIO1 __builtin_amdgcn_s_setprio(1)
#define PRIO0 __builtin_amdgcn_s_setprio(0)

// ---------------- prep: f32 -> bf16 (vectorized x4) ----------------
__global__ void k_cvt(const float* __restrict__ in, bf16* __restrict__ out, int n4) {
  int i = blockIdx.x * blockDim.x + threadIdx.x;
  if (i < n4) {
    float4 v = ((const float4*)in)[i];
    bf16* o = out + (size_t)i * 4;
    o[0] = __float2bfloat16(v.x);
    o[1] = __float2bfloat16(v.y);
    o[2] = __float2bfloat16(v.z);
    o[3] = __float2bfloat16(v.w);
  }
}

// ---------------- prep: transpose f32 [R][C] -> bf16 [C][R] ----------------
__global__ __launch_bounds__(256)
void k_transpose(const float* __restrict__ in, bf16* __restrict__ out, int R, int C) {
  __shared__ float t[32][33];
  const int c0 = blockIdx.x * 32, r0 = blockIdx.y * 32;
  const int tx = threadIdx.x & 31;
  const int ty = threadIdx.x >> 5;   // 0..7
#pragma unroll
  for (int i = 0; i < 4; ++i)
    t[ty + 8*i][tx] = in[(size_t)(r0 + ty + 8*i) * C + c0 + tx];
  __syncthreads();
#pragma unroll
  for (int i = 0; i < 4; ++i)
    out[(size_t)(c0 + ty + 8*i) * R + r0 + tx] = __float2bfloat16(t[tx][ty + 8*i]);
}

// ====== 128x128 GEMM, BK=32, 3-buffer pipeline, 3 blocks/CU (r16-exact) ======
// r12-proven skeleton: 8 waves 2Mx4N, lockstep tile, distributed staging +
// collective barrier per tile [r8 lesson], mod-3 rotation with depth-2
// staging [r12 safety], slot swizzle [r6, 0-conflict], square XCD chunking
// [r12: per-XCD A panel L2-fits]. No explicit lgkm drain before MFMAs
// (compiler emits fine-grained lgkmcnt per frag->MFMA dep).
// vmcnt(2)+barrier at tile end: publishes tile t+1 collectively.
// EPI==1: RoPE + scatter Q/K row-major + V^T ; EPI==2: bias + f32 out.
template<int EPI>
__global__ __launch_bounds__(512, 4)
void k_gemmP(const bf16* __restrict__ A, const bf16* __restrict__ BT,
             int M, int N, int K,
             float* __restrict__ Cout, const float* __restrict__ bias,
             bf16* __restrict__ Qb, bf16* __restrict__ Kb, bf16* __restrict__ VTb,
             const float* __restrict__ cosT, const float* __restrict__ sinT)
{
  constexpr int ABUF = 8192;           // one A tile (128 rows x 64B)
  constexpr int BBUF = 8192;
  constexpr int AREG = 3 * ABUF;       // 24576
  extern __shared__ char smem[];       // 49152 B

  const int tid = threadIdx.x;
  const int wid = tid >> 6, lane = tid & 63;
  const int wm = wid >> 2, wn = wid & 3;       // wave grid 2(M) x 4(N)
  const int lr = lane & 15, lkg = lane >> 4;

  // XCD chunk map (bid%8 = XCD): XCD=(mquarter, nhalf) owns an
  // 8 m-tile x (nbx/2) n-tile chunk, m-inner traversal (A panel L2-fits).
  const int nbx = N >> 7;
  const int xcd = blockIdx.x & 7;
  const int i   = blockIdx.x >> 3;
  const int m0 = (((xcd >> 1) << 3) + (i & 7)) << 7;
  const int n0 = ((xcd & 1) * (nbx >> 1) + (i >> 3)) << 7;

  // staging: wave wid owns 16 rows; source slot carries inverse swizzle
  const int scol = ((lane & 3) ^ ((lane >> 3) & 3)) * 8;   // bf16 elems
  const bf16* Asrc = A  + (size_t)(m0 + wid*16 + (lane >> 2)) * K + scol;
  const bf16* Bsrc = BT + (size_t)(n0 + wid*16 + (lane >> 2)) * K + scol;

  auto stageA = [&](int t) {
    gl_lds16(Asrc + t*32, smem + (t % 3)*ABUF + wid*1024);
  };
  auto stageB = [&](int t) {
    gl_lds16(Bsrc + t*32, smem + AREG + (t % 3)*BBUF + wid*1024);
  };

  // ds_read fragment bases (row = 64B, slot XOR-swizzled by row bits 1-2)
  const int slotX = (lkg ^ ((lr >> 1) & 3)) * 16;
  const int aBase = wm*4096 + lr*64 + slotX;   // rows wm*64 + mf*16 + lr
  const int bBase = wn*2048 + lr*64 + slotX;   // rows wn*32 + nf*16 + lr

  const f32x4 vzero = {0.f, 0.f, 0.f, 0.f};
  f32x4 acc[4][2];
#pragma unroll
  for (int ii = 0; ii < 4; ++ii)
#pragma unroll
    for (int j = 0; j < 2; ++j) acc[ii][j] = vzero;

  const int nt = K >> 5;              // K-tiles of 32 (>= 3)

  // prologue: stage tiles 0,1 -> wait until tile 0's 2 loads complete
  stageA(0); stageB(0); stageA(1); stageB(1);
  asm volatile("s_waitcnt vmcnt(2)" ::: "memory");
  SCHED0; BARRIER;

  for (int t = 0; t < nt; ++t) {
    const int bufA = (t % 3) * ABUF;
    const int bufB = AREG + (t % 3) * BBUF;
    const int ts   = (t + 2 < nt) ? t + 2 : nt - 1;   // clamp: same-data dup
    bf16x8 aFr[4], bFr[2];

#pragma unroll
    for (int mf = 0; mf < 4; ++mf)
      aFr[mf] = *(const bf16x8*)(smem + bufA + aBase + mf*1024);
#pragma unroll
    for (int nf = 0; nf < 2; ++nf)
      bFr[nf] = *(const bf16x8*)(smem + bufB + bBase + nf*1024);
    stageA(ts); stageB(ts);

    // no explicit lgkm drain: compiler emits fine-grained lgkmcnt per dep
    PRIO1;
#pragma unroll
    for (int mf = 0; mf < 4; ++mf)
#pragma unroll
      for (int nf = 0; nf < 2; ++nf)
        acc[mf][nf] = mfma16(aFr[mf], bFr[nf], acc[mf][nf]);
    PRIO0;
    // complete tile t+1's loads (only stage(t+2)'s 2 loads stay in flight)
    asm volatile("s_waitcnt vmcnt(2)" ::: "memory");
    SCHED0;
    BARRIER;                          // collective: tile t+1 visible to all
  }

  if constexpr (EPI == 1) {
    const float inv_sqrt_d = 0.08838834764831845f;  // 1/sqrt(128)
#pragma unroll
    for (int nf = 0; nf < 2; ++nf) {
      const int gcb = n0 + wn*32 + nf*16;           // wave-uniform, mult of 16
      const int section = gcb >> 11;                // 0=q 1=k 2=v
      const int cc = (gcb & 2047) + lr;
      const int h = cc >> 7, d = cc & 127;
#pragma unroll
      for (int mf = 0; mf < 4; ++mf) {
#pragma unroll
        for (int reg = 0; reg < 4; ++reg) {
          const int grow = m0 + wm*64 + mf*16 + lkg*4 + reg;
          const int bidx = grow >> 11, lseq = grow & 2047;
          float val = acc[mf][nf][reg];
          if (section < 2) {
            float p = __shfl_xor(val, 1);           // RoPE pair partner
            const int fi = d >> 1;
            float cv = cosT[(size_t)lseq * 64 + fi];
            float sv = sinT[(size_t)lseq * 64 + fi];
            float r = (d & 1) ? fmaf(p, sv, val * cv)
                              : fmaf(val, cv, -p * sv);
            if (section == 0) {
              r *= inv_sqrt_d;
              Qb[((size_t)(bidx*NHEAD + h) * LL + lseq) * HDIM + d] = __float2bfloat16(r);
            } else {
              Kb[((size_t)(bidx*NHEAD + h) * LL + lseq) * HDIM + d] = __float2bfloat16(r);
            }
          } else {
            VTb[((size_t)(bidx*NHEAD + h) * HDIM + d) * LL + lseq] = __float2bfloat16(val);
          }
        }
      }
    }
  } else {
#pragma unroll
    for (int nf = 0; nf < 2; ++nf) {
      const int gcol = n0 + wn*32 + nf*16 + lr;
      const float bv = bias[gcol];
#pragma unroll
      for (int mf = 0; mf < 4; ++mf) {
#pragma unroll
        for (int reg = 0; reg < 4; ++reg) {
          const int grow = m0 + wm*64 + mf*16 + lkg*4 + reg;
          Cout[(size_t)grow * N + gcol] = acc[mf][nf][reg] + bv;
        }
      }
    }
  }
}

// ---------------- flash attention (r14-exact): swapped QK^T ----------------
// s2 = mfma(K,Q): lane (lr,lkg) holds S[q=lr][kv=c*16+lkg*4+reg] -> row
// softmax is 16 lane-local values + 2 shfl. P packs 4 bf16 -> b64 writes.
// Balanced q-tile pairing (r9): block bx does (15-bx) then bx.
__global__ __launch_bounds__(256, 2)
void k_attn(const bf16* __restrict__ Qb, const bf16* __restrict__ Kb,
            const bf16* __restrict__ VTb, bf16* __restrict__ attnA)
{
  __shared__ bf16 Ks[64][136];
  __shared__ bf16 Vs[128][72];
  __shared__ bf16 Ps[4][32][72];

  const int bh  = blockIdx.y;
  const int bx  = blockIdx.x;                 // 0..7
  const int tid = threadIdx.x;
  const int wid = tid >> 6, lane = tid & 63;
  const int lr  = lane & 15, lkg = lane >> 4;

  const bf16* Qh = Qb  + (size_t)bh * LL * HDIM;
  const bf16* Kh = Kb  + (size_t)bh * LL * HDIM;
  const bf16* Vh = VTb + (size_t)bh * HDIM * LL;
  const int b = bh >> 4, h = bh & 15;
  const f32x4 vzero = {0.f, 0.f, 0.f, 0.f};

  for (int pp = 0; pp < 2; ++pp) {
    const int qt  = pp ? bx : (15 - bx);      // heavy tile first
    const int Q0  = qt * 128;
    const int q0w = Q0 + wid * 32;

    bf16x8 qf[2][4];
#pragma unroll
    for (int qr = 0; qr < 2; ++qr)
#pragma unroll
      for (int kk = 0; kk < 4; ++kk)
        qf[qr][kk] = *(const bf16x8*)(Qh + (size_t)(q0w + qr*16 + lr) * HDIM + kk*32 + lkg*8);

    f32x4 oacc[2][8];
#pragma unroll
    for (int qr = 0; qr < 2; ++qr)
#pragma unroll
      for (int db = 0; db < 8; ++db) oacc[qr][db] = vzero;
    float ml[2] = {-INFINITY, -INFINITY};
    float ll[2] = {0.f, 0.f};

    const int NT = Q0 / 64 + 2;
    bf16x8 kpre[4], vpre[4];
#pragma unroll
    for (int j = 0; j < 4; ++j) {
      const int c = j*256 + tid;
      kpre[j] = *(const bf16x8*)(Kh + (size_t)(c >> 4) * HDIM + (c & 15) * 8);
      vpre[j] = *(const bf16x8*)(Vh + (size_t)(c >> 3) * LL + (c & 7) * 8);
    }

    for (int kt = 0; kt < NT; ++kt) {
      const int kbase = kt * 64;
      __syncthreads();
#pragma unroll
      for (int j = 0; j < 4; ++j) {
        const int c = j*256 + tid;
        *(bf16x8*)&Ks[c >> 4][(c & 15) * 8] = kpre[j];
        *(bf16x8*)&Vs[c >> 3][(c & 7) * 8]  = vpre[j];
      }
      __syncthreads();
      if (kt + 1 < NT) {
#pragma unroll
        for (int j = 0; j < 4; ++j) {
          const int c = j*256 + tid;
          kpre[j] = *(const bf16x8*)(Kh + (size_t)((kt+1)*64 + (c >> 4)) * HDIM + (c & 15) * 8);
          vpre[j] = *(const bf16x8*)(Vh + (size_t)(c >> 3) * LL + (kt+1)*64 + (c & 7) * 8);
        }
      }
      if (kbase <= q0w + 31) {
        f32x4 s2[2][4];
#pragma unroll
        for (int qr = 0; qr < 2; ++qr)
#pragma unroll
          for (int c = 0; c < 4; ++c) s2[qr][c] = vzero;
#pragma unroll
        for (int c = 0; c < 4; ++c) {
          bf16x8 kf[4];
#pragma unroll
          for (int kk = 0; kk < 4; ++kk)
            kf[kk] = *(const bf16x8*)&Ks[c*16 + lr][kk*32 + lkg*8];
#pragma unroll
          for (int qr = 0; qr < 2; ++qr)
#pragma unroll
            for (int kk = 0; kk < 4; ++kk)
              s2[qr][c] = mfma16(kf[kk], qf[qr][kk], s2[qr][c]);
        }
#pragma unroll
        for (int qr = 0; qr < 2; ++qr) {
          const int qrow = q0w + qr*16 + lr;
          float pv[4][4];
#pragma unroll
          for (int c = 0; c < 4; ++c)
#pragma unroll
            for (int reg = 0; reg < 4; ++reg) {
              const int kv = kbase + c*16 + lkg*4 + reg;
              pv[c][reg] = (kv <= qrow) ? s2[qr][c][reg] : -INFINITY;
            }
          float tm = pv[0][0];
#pragma unroll
          for (int c = 0; c < 4; ++c)
#pragma unroll
            for (int reg = 0; reg < 4; ++reg)
              if (c || reg) tm = fmaxf(tm, pv[c][reg]);
          tm = fmaxf(tm, __shfl_xor(tm, 16));
          tm = fmaxf(tm, __shfl_xor(tm, 32));
          const float mnew = fmaxf(ml[qr], tm);
          const float scl  = __expf(ml[qr] - mnew);
          ml[qr] = mnew;
          float rs = 0.f;
#pragma unroll
          for (int c = 0; c < 4; ++c)
#pragma unroll
            for (int reg = 0; reg < 4; ++reg) {
              pv[c][reg] = __expf(pv[c][reg] - mnew);
              rs += pv[c][reg];
            }
          rs += __shfl_xor(rs, 16);
          rs += __shfl_xor(rs, 32);
          ll[qr] = ll[qr] * scl + rs;
#pragma unroll
          for (int c = 0; c < 4; ++c) {
            unsigned lo = bfu(pv[c][0]) | (bfu(pv[c][1]) << 16);
            unsigned hi = bfu(pv[c][2]) | (bfu(pv[c][3]) << 16);
            *(uint2*)&Ps[wid][qr*16 + lr][c*16 + lkg*4] = make_uint2(lo, hi);
          }
          float sr[4];
#pragma unroll
          for (int reg = 0; reg < 4; ++reg) sr[reg] = __shfl(scl, lkg*4 + reg);
#pragma unroll
          for (int db = 0; db < 8; ++db) {
            oacc[qr][db][0] *= sr[0]; oacc[qr][db][1] *= sr[1];
            oacc[qr][db][2] *= sr[2]; oacc[qr][db][3] *= sr[3];
          }
        }
        asm volatile("s_waitcnt lgkmcnt(0)" ::: "memory");
        __builtin_amdgcn_sched_barrier(0);
        bf16x8 pf[2][2];
#pragma unroll
        for (int qr = 0; qr < 2; ++qr)
#pragma unroll
          for (int k2 = 0; k2 < 2; ++k2)
            pf[qr][k2] = *(const bf16x8*)&Ps[wid][qr*16 + lr][k2*32 + lkg*8];
#pragma unroll
        for (int db = 0; db < 8; ++db) {
          bf16x8 vf0 = *(const bf16x8*)&Vs[db*16 + lr][lkg*8];
          bf16x8 vf1 = *(const bf16x8*)&Vs[db*16 + lr][32 + lkg*8];
#pragma unroll
          for (int qr = 0; qr < 2; ++qr) {
            oacc[qr][db] = mfma16(pf[qr][0], vf0, oacc[qr][db]);
            oacc[qr][db] = mfma16(pf[qr][1], vf1, oacc[qr][db]);
          }
        }
      }
    }

#pragma unroll
    for (int qr = 0; qr < 2; ++qr) {
      const float myinv = 1.0f / ll[qr];
      float li[4];
#pragma unroll
      for (int reg = 0; reg < 4; ++reg) li[reg] = __shfl(myinv, lkg*4 + reg);
#pragma unroll
      for (int reg = 0; reg < 4; ++reg) {
        const int row = q0w + qr*16 + lkg*4 + reg;
        bf16* dst = attnA + ((size_t)(b*LL + row)) * MODEL + h * HDIM;
#pragma unroll
        for (int db = 0; db < 8; ++db)
          dst[db*16 + lr] = __float2bfloat16(oacc[qr][db][reg] * li[reg]);
      }
    }
  }
}

// ---------------- launch ----------------
extern "C" void kernel_launch(void* const* d_in, const int* in_sizes, int n_in,
                              void* d_out, int out_size, void* d_ws, size_t ws_size,
                              hipStream_t stream)
{
  const float* x    = (const float*)d_in[0];
  const float* cosT = (const float*)d_in[1];
  const float* sinT = (const float*)d_in[2];
  const float* Wqkv = (const float*)d_in[3];
  const float* Wc   = (const float*)d_in[4];
  const float* bc   = (const float*)d_in[5];
  float* out = (float*)d_out;

  // workspace layout (bytes):
  //   x16    @ 0         : 16,777,216   (reused as attnA later)
  //   WqkvT  @ 16777216  : 25,165,824
  //   WcT    @ 41943040  :  8,388,608
  //   Qb     @ 50331648  : 16,777,216
  //   Kb     @ 67108864  : 16,777,216
  //   VTb    @ 83886080  : 16,777,216   -> total 100,663,296 B
  if (ws_size < 100663296u) return;
  char* w = (char*)d_ws;
  bf16* x16   = (bf16*)(w);
  bf16* WqkvT = (bf16*)(w + (size_t)16777216);
  bf16* WcT   = (bf16*)(w + (size_t)41943040);
  bf16* Qb    = (bf16*)(w + (size_t)50331648);
  bf16* Kb    = (bf16*)(w + (size_t)67108864);
  bf16* VTb   = (bf16*)(w + (size_t)83886080);
  bf16* attnA = x16;   // overlay: x16 dead after GEMM1

  // allow 48KB dynamic LDS (idempotent; not a stream op -> capture-safe)
  hipFuncSetAttribute(reinterpret_cast<const void*>(&k_gemmP<1>),
                      hipFuncAttributeMaxDynamicSharedMemorySize, 49152);
  hipFuncSetAttribute(reinterpret_cast<const void*>(&k_gemmP<2>),
                      hipFuncAttributeMaxDynamicSharedMemorySize, 49152);

  k_cvt<<<(MTOT*MODEL/4 + 255)/256, 256, 0, stream>>>(x, x16, MTOT*MODEL/4);
  k_transpose<<<dim3(N1/32,    MODEL/32), 256, 0, stream>>>(Wqkv, WqkvT, MODEL, N1);
  k_transpose<<<dim3(MODEL/32, MODEL/32), 256, 0, stream>>>(Wc,   WcT,   MODEL, MODEL);

  // grid 48*32 = 1536 blocks (3 blocks/CU -> 2 exact rounds of 768)
  k_gemmP<1><<<(N1/128)*(MTOT/128), 512, 49152, stream>>>(
      x16, WqkvT, MTOT, N1, MODEL,
      nullptr, nullptr, Qb, Kb, VTb, cosT, sinT);

  // grid 8*32 = 256 blocks, uniform 17 tile-units each
  k_attn<<<dim3(8, BB*NHEAD), 256, 0, stream>>>(Qb, Kb, VTb, attnA);

  // grid 16*32 = 512 blocks
  k_gemmP<2><<<(MODEL/128)*(MTOT/128), 512, 49152, stream>>>(
      attnA, WcT, MTOT, MODEL, MODEL,
      out, bc, nullptr, nullptr, nullptr, nullptr, nullptr);
}

// Round 20
// 287.445 us; speedup vs baseline: 2.3633x; 1.0322x over previous
//
#include <hip/hip_runtime.h>
#include <hip/hip_bf16.h>

#define MODEL 2048
#define NHEAD 16
#define HDIM  128
#define BB    2
#define LL    2048
#define N1    (3*MODEL)      // 6144
#define MTOT  (BB*LL)        // 4096

typedef __hip_bfloat16 bf16;
typedef __attribute__((ext_vector_type(8))) short bf16x8;
typedef __attribute__((ext_vector_type(4))) float f32x4;

static __device__ __forceinline__ f32x4 mfma16(bf16x8 a, bf16x8 b, f32x4 c) {
  return __builtin_amdgcn_mfma_f32_16x16x32_bf16(a, b, c, 0, 0, 0);
}

// async global->LDS DMA, 16B per lane; LDS base wave-uniform, dest linear
static __device__ __forceinline__ void gl_lds16(const void* g, void* l) {
  __builtin_amdgcn_global_load_lds(
      (const __attribute__((address_space(1))) unsigned int*)g,
      (__attribute__((address_space(3))) unsigned int*)l, 16, 0, 0);
}

static __device__ __forceinline__ unsigned bfu(float x) {
  bf16 b = __float2bfloat16(x);
  return (unsigned)*reinterpret_cast<unsigned short*>(&b);
}

#define BARRIER __builtin_amdgcn_s_barrier()
#define SCHED0  __builtin_amdgcn_sched_barrier(0)
#define PRIO1 __builtin_amdgcn_s_setprio(1)
#define PRIO0 __builtin_amdgcn_s_setprio(0)

// ---------------- prep: f32 -> bf16 (vectorized x4) ----------------
__global__ void k_cvt(const float* __restrict__ in, bf16* __restrict__ out, int n4) {
  int i = blockIdx.x * blockDim.x + threadIdx.x;
  if (i < n4) {
    float4 v = ((const float4*)in)[i];
    bf16* o = out + (size_t)i * 4;
    o[0] = __float2bfloat16(v.x);
    o[1] = __float2bfloat16(v.y);
    o[2] = __float2bfloat16(v.z);
    o[3] = __float2bfloat16(v.w);
  }
}

// ---------------- prep: transpose f32 [R][C] -> bf16 [C][R] ----------------
__global__ __launch_bounds__(256)
void k_transpose(const float* __restrict__ in, bf16* __restrict__ out, int R, int C) {
  __shared__ float t[32][33];
  const int c0 = blockIdx.x * 32, r0 = blockIdx.y * 32;
  const int tx = threadIdx.x & 31;
  const int ty = threadIdx.x >> 5;   // 0..7
#pragma unroll
  for (int i = 0; i < 4; ++i)
    t[ty + 8*i][tx] = in[(size_t)(r0 + ty + 8*i) * C + c0 + tx];
  __syncthreads();
#pragma unroll
  for (int i = 0; i < 4; ++i)
    out[(size_t)(c0 + ty + 8*i) * R + r0 + tx] = __float2bfloat16(t[tx][ty + 8*i]);
}

// ====== 128x128 GEMM, BK=32, 3-buffer pipeline, 3 blocks/CU (r16-exact) ======
// r12-proven skeleton: 8 waves 2Mx4N, lockstep tile, distributed staging +
// collective barrier per tile [r8 lesson], mod-3 rotation with depth-2
// staging [r12 safety], slot swizzle [r6, 0-conflict], square XCD chunking
// [r12: per-XCD A panel L2-fits].
// EPI==1: RoPE + scatter Q/K row-major + V^T ; EPI==2: bias + f32 out.
template<int EPI>
__global__ __launch_bounds__(512, 4)
void k_gemmP(const bf16* __restrict__ A, const bf16* __restrict__ BT,
             int M, int N, int K,
             float* __restrict__ Cout, const float* __restrict__ bias,
             bf16* __restrict__ Qb, bf16* __restrict__ Kb, bf16* __restrict__ VTb,
             const float* __restrict__ cosT, const float* __restrict__ sinT)
{
  constexpr int ABUF = 8192;           // one A tile (128 rows x 64B)
  constexpr int BBUF = 8192;
  constexpr int AREG = 3 * ABUF;       // 24576
  extern __shared__ char smem[];       // 49152 B

  const int tid = threadIdx.x;
  const int wid = tid >> 6, lane = tid & 63;
  const int wm = wid >> 2, wn = wid & 3;       // wave grid 2(M) x 4(N)
  const int lr = lane & 15, lkg = lane >> 4;

  // XCD chunk map (bid%8 = XCD): XCD=(mquarter, nhalf) owns an
  // 8 m-tile x (nbx/2) n-tile chunk, m-inner traversal (A panel L2-fits).
  const int nbx = N >> 7;
  const int xcd = blockIdx.x & 7;
  const int i   = blockIdx.x >> 3;
  const int m0 = (((xcd >> 1) << 3) + (i & 7)) << 7;
  const int n0 = ((xcd & 1) * (nbx >> 1) + (i >> 3)) << 7;

  // staging: wave wid owns 16 rows; source slot carries inverse swizzle
  const int scol = ((lane & 3) ^ ((lane >> 3) & 3)) * 8;   // bf16 elems
  const bf16* Asrc = A  + (size_t)(m0 + wid*16 + (lane >> 2)) * K + scol;
  const bf16* Bsrc = BT + (size_t)(n0 + wid*16 + (lane >> 2)) * K + scol;

  auto stageA = [&](int t) {
    gl_lds16(Asrc + t*32, smem + (t % 3)*ABUF + wid*1024);
  };
  auto stageB = [&](int t) {
    gl_lds16(Bsrc + t*32, smem + AREG + (t % 3)*BBUF + wid*1024);
  };

  // ds_read fragment bases (row = 64B, slot XOR-swizzled by row bits 1-2)
  const int slotX = (lkg ^ ((lr >> 1) & 3)) * 16;
  const int aBase = wm*4096 + lr*64 + slotX;   // rows wm*64 + mf*16 + lr
  const int bBase = wn*2048 + lr*64 + slotX;   // rows wn*32 + nf*16 + lr

  const f32x4 vzero = {0.f, 0.f, 0.f, 0.f};
  f32x4 acc[4][2];
#pragma unroll
  for (int ii = 0; ii < 4; ++ii)
#pragma unroll
    for (int j = 0; j < 2; ++j) acc[ii][j] = vzero;

  const int nt = K >> 5;              // K-tiles of 32 (>= 3)

  // prologue: stage tiles 0,1 -> wait until tile 0's 2 loads complete
  stageA(0); stageB(0); stageA(1); stageB(1);
  asm volatile("s_waitcnt vmcnt(2)" ::: "memory");
  SCHED0; BARRIER;

  for (int t = 0; t < nt; ++t) {
    const int bufA = (t % 3) * ABUF;
    const int bufB = AREG + (t % 3) * BBUF;
    const int ts   = (t + 2 < nt) ? t + 2 : nt - 1;   // clamp: same-data dup
    bf16x8 aFr[4], bFr[2];

#pragma unroll
    for (int mf = 0; mf < 4; ++mf)
      aFr[mf] = *(const bf16x8*)(smem + bufA + aBase + mf*1024);
#pragma unroll
    for (int nf = 0; nf < 2; ++nf)
      bFr[nf] = *(const bf16x8*)(smem + bufB + bBase + nf*1024);
    stageA(ts); stageB(ts);

    // no explicit lgkm drain: compiler emits fine-grained lgkmcnt per dep
    PRIO1;
#pragma unroll
    for (int mf = 0; mf < 4; ++mf)
#pragma unroll
      for (int nf = 0; nf < 2; ++nf)
        acc[mf][nf] = mfma16(aFr[mf], bFr[nf], acc[mf][nf]);
    PRIO0;
    // complete tile t+1's loads (only stage(t+2)'s 2 loads stay in flight)
    asm volatile("s_waitcnt vmcnt(2)" ::: "memory");
    SCHED0;
    BARRIER;                          // collective: tile t+1 visible to all
  }

  if constexpr (EPI == 1) {
    const float inv_sqrt_d = 0.08838834764831845f;  // 1/sqrt(128)
#pragma unroll
    for (int nf = 0; nf < 2; ++nf) {
      const int gcb = n0 + wn*32 + nf*16;           // wave-uniform, mult of 16
      const int section = gcb >> 11;                // 0=q 1=k 2=v
      const int cc = (gcb & 2047) + lr;
      const int h = cc >> 7, d = cc & 127;
#pragma unroll
      for (int mf = 0; mf < 4; ++mf) {
#pragma unroll
        for (int reg = 0; reg < 4; ++reg) {
          const int grow = m0 + wm*64 + mf*16 + lkg*4 + reg;
          const int bidx = grow >> 11, lseq = grow & 2047;
          float val = acc[mf][nf][reg];
          if (section < 2) {
            float p = __shfl_xor(val, 1);           // RoPE pair partner
            const int fi = d >> 1;
            float cv = cosT[(size_t)lseq * 64 + fi];
            float sv = sinT[(size_t)lseq * 64 + fi];
            float r = (d & 1) ? fmaf(p, sv, val * cv)
                              : fmaf(val, cv, -p * sv);
            if (section == 0) {
              r *= inv_sqrt_d;
              Qb[((size_t)(bidx*NHEAD + h) * LL + lseq) * HDIM + d] = __float2bfloat16(r);
            } else {
              Kb[((size_t)(bidx*NHEAD + h) * LL + lseq) * HDIM + d] = __float2bfloat16(r);
            }
          } else {
            VTb[((size_t)(bidx*NHEAD + h) * HDIM + d) * LL + lseq] = __float2bfloat16(val);
          }
        }
      }
    }
  } else {
#pragma unroll
    for (int nf = 0; nf < 2; ++nf) {
      const int gcol = n0 + wn*32 + nf*16 + lr;
      const float bv = bias[gcol];
#pragma unroll
      for (int mf = 0; mf < 4; ++mf) {
#pragma unroll
        for (int reg = 0; reg < 4; ++reg) {
          const int grow = m0 + wm*64 + mf*16 + lkg*4 + reg;
          Cout[(size_t)grow * N + gcol] = acc[mf][nf][reg] + bv;
        }
      }
    }
  }
}

// ---------------- flash attention (r20): merged pair, 8 waves/block --------
// Waves 0-3 own q-tile (15-bx), waves 4-7 own q-tile bx; each staged K/V
// tile serves BOTH tiles (KV staged once per block: 100 vs 136 stagings per
// bh; critical path 32 vs 34 iters; 8 waves resident vs 4). Per-wave body =
// r14-verified swapped-QK^T lane-local softmax, only LDS bases changed.
// Work per block uniform by pairing (r9 lesson); all 512 threads hit every
// barrier (causal check skips compute only).
__global__ __launch_bounds__(512)
void k_attn(const bf16* __restrict__ Qb, const bf16* __restrict__ Kb,
            const bf16* __restrict__ VTb, bf16* __restrict__ attnA)
{
  extern __shared__ char asmem[];
  bf16* Ks = (bf16*)asmem;                      // [64][136]  17408 B
  bf16* Vs = (bf16*)(asmem + 17408);            // [128][72]  18432 B
  bf16* Ps = (bf16*)(asmem + 17408 + 18432);    // [8][32][72] 36864 B

  const int bh  = blockIdx.y;
  const int bx  = blockIdx.x;                 // 0..7
  const int tid = threadIdx.x;                // 0..511
  const int wid = tid >> 6, lane = tid & 63;
  const int lr  = lane & 15, lkg = lane >> 4;

  const bf16* Qh = Qb  + (size_t)bh * LL * HDIM;
  const bf16* Kh = Kb  + (size_t)bh * LL * HDIM;
  const bf16* Vh = VTb + (size_t)bh * HDIM * LL;
  const int b = bh >> 4, h = bh & 15;
  const f32x4 vzero = {0.f, 0.f, 0.f, 0.f};

  const int qt  = (wid < 4) ? (15 - bx) : bx;   // heavy tile on waves 0-3
  const int q0w = qt * 128 + (wid & 3) * 32;

  bf16x8 qf[2][4];
#pragma unroll
  for (int qr = 0; qr < 2; ++qr)
#pragma unroll
    for (int kk = 0; kk < 4; ++kk)
      qf[qr][kk] = *(const bf16x8*)(Qh + (size_t)(q0w + qr*16 + lr) * HDIM + kk*32 + lkg*8);

  f32x4 oacc[2][8];
#pragma unroll
  for (int qr = 0; qr < 2; ++qr)
#pragma unroll
    for (int db = 0; db < 8; ++db) oacc[qr][db] = vzero;
  float ml[2] = {-INFINITY, -INFINITY};
  float ll[2] = {0.f, 0.f};

  const int NT = (15 - bx) * 2 + 2;   // heavy tile's kv-tile count (max)

  bf16x8 kpre[2], vpre[2];
#pragma unroll
  for (int j = 0; j < 2; ++j) {
    const int c = j*512 + tid;
    kpre[j] = *(const bf16x8*)(Kh + (size_t)(c >> 4) * HDIM + (c & 15) * 8);
    vpre[j] = *(const bf16x8*)(Vh + (size_t)(c >> 3) * LL + (c & 7) * 8);
  }

  for (int kt = 0; kt < NT; ++kt) {
    const int kbase = kt * 64;
    __syncthreads();
#pragma unroll
    for (int j = 0; j < 2; ++j) {
      const int c = j*512 + tid;
      *(bf16x8*)&Ks[(c >> 4) * 136 + (c & 15) * 8] = kpre[j];
      *(bf16x8*)&Vs[(c >> 3) * 72  + (c & 7)  * 8] = vpre[j];
    }
    __syncthreads();
    if (kt + 1 < NT) {
#pragma unroll
      for (int j = 0; j < 2; ++j) {
        const int c = j*512 + tid;
        kpre[j] = *(const bf16x8*)(Kh + (size_t)((kt+1)*64 + (c >> 4)) * HDIM + (c & 15) * 8);
        vpre[j] = *(const bf16x8*)(Vh + (size_t)(c >> 3) * LL + (kt+1)*64 + (c & 7) * 8);
      }
    }
    if (kbase <= q0w + 31) {
      f32x4 s2[2][4];
#pragma unroll
      for (int qr = 0; qr < 2; ++qr)
#pragma unroll
        for (int c = 0; c < 4; ++c) s2[qr][c] = vzero;
#pragma unroll
      for (int c = 0; c < 4; ++c) {
        bf16x8 kf[4];
#pragma unroll
        for (int kk = 0; kk < 4; ++kk)
          kf[kk] = *(const bf16x8*)&Ks[(c*16 + lr) * 136 + kk*32 + lkg*8];
#pragma unroll
        for (int qr = 0; qr < 2; ++qr)
#pragma unroll
          for (int kk = 0; kk < 4; ++kk)
            s2[qr][c] = mfma16(kf[kk], qf[qr][kk], s2[qr][c]);
      }
#pragma unroll
      for (int qr = 0; qr < 2; ++qr) {
        const int qrow = q0w + qr*16 + lr;
        float pv[4][4];
#pragma unroll
        for (int c = 0; c < 4; ++c)
#pragma unroll
          for (int reg = 0; reg < 4; ++reg) {
            const int kv = kbase + c*16 + lkg*4 + reg;
            pv[c][reg] = (kv <= qrow) ? s2[qr][c][reg] : -INFINITY;
          }
        float tm = pv[0][0];
#pragma unroll
        for (int c = 0; c < 4; ++c)
#pragma unroll
          for (int reg = 0; reg < 4; ++reg)
            if (c || reg) tm = fmaxf(tm, pv[c][reg]);
        tm = fmaxf(tm, __shfl_xor(tm, 16));
        tm = fmaxf(tm, __shfl_xor(tm, 32));
        const float mnew = fmaxf(ml[qr], tm);
        const float scl  = __expf(ml[qr] - mnew);
        ml[qr] = mnew;
        float rs = 0.f;
#pragma unroll
        for (int c = 0; c < 4; ++c)
#pragma unroll
          for (int reg = 0; reg < 4; ++reg) {
            pv[c][reg] = __expf(pv[c][reg] - mnew);
            rs += pv[c][reg];
          }
        rs += __shfl_xor(rs, 16);
        rs += __shfl_xor(rs, 32);
        ll[qr] = ll[qr] * scl + rs;
#pragma unroll
        for (int c = 0; c < 4; ++c) {
          unsigned lo = bfu(pv[c][0]) | (bfu(pv[c][1]) << 16);
          unsigned hi = bfu(pv[c][2]) | (bfu(pv[c][3]) << 16);
          *(uint2*)&Ps[(wid*32 + qr*16 + lr) * 72 + c*16 + lkg*4] = make_uint2(lo, hi);
        }
        float sr[4];
#pragma unroll
        for (int reg = 0; reg < 4; ++reg) sr[reg] = __shfl(scl, lkg*4 + reg);
#pragma unroll
        for (int db = 0; db < 8; ++db) {
          oacc[qr][db][0] *= sr[0]; oacc[qr][db][1] *= sr[1];
          oacc[qr][db][2] *= sr[2]; oacc[qr][db][3] *= sr[3];
        }
      }
      asm volatile("s_waitcnt lgkmcnt(0)" ::: "memory");
      __builtin_amdgcn_sched_barrier(0);
      bf16x8 pf[2][2];
#pragma unroll
      for (int qr = 0; qr < 2; ++qr)
#pragma unroll
        for (int k2 = 0; k2 < 2; ++k2)
          pf[qr][k2] = *(const bf16x8*)&Ps[(wid*32 + qr*16 + lr) * 72 + k2*32 + lkg*8];
#pragma unroll
      for (int db = 0; db < 8; ++db) {
        bf16x8 vf0 = *(const bf16x8*)&Vs[(db*16 + lr) * 72 + lkg*8];
        bf16x8 vf1 = *(const bf16x8*)&Vs[(db*16 + lr) * 72 + 32 + lkg*8];
#pragma unroll
        for (int qr = 0; qr < 2; ++qr) {
          oacc[qr][db] = mfma16(pf[qr][0], vf0, oacc[qr][db]);
          oacc[qr][db] = mfma16(pf[qr][1], vf1, oacc[qr][db]);
        }
      }
    }
  }

#pragma unroll
  for (int qr = 0; qr < 2; ++qr) {
    const float myinv = 1.0f / ll[qr];
    float li[4];
#pragma unroll
    for (int reg = 0; reg < 4; ++reg) li[reg] = __shfl(myinv, lkg*4 + reg);
#pragma unroll
    for (int reg = 0; reg < 4; ++reg) {
      const int row = q0w + qr*16 + lkg*4 + reg;
      bf16* dst = attnA + ((size_t)(b*LL + row)) * MODEL + h * HDIM;
#pragma unroll
      for (int db = 0; db < 8; ++db)
        dst[db*16 + lr] = __float2bfloat16(oacc[qr][db][reg] * li[reg]);
    }
  }
}

// ---------------- launch ----------------
extern "C" void kernel_launch(void* const* d_in, const int* in_sizes, int n_in,
                              void* d_out, int out_size, void* d_ws, size_t ws_size,
                              hipStream_t stream)
{
  const float* x    = (const float*)d_in[0];
  const float* cosT = (const float*)d_in[1];
  const float* sinT = (const float*)d_in[2];
  const float* Wqkv = (const float*)d_in[3];
  const float* Wc   = (const float*)d_in[4];
  const float* bc   = (const float*)d_in[5];
  float* out = (float*)d_out;

  // workspace layout (bytes):
  //   x16    @ 0         : 16,777,216   (reused as attnA later)
  //   WqkvT  @ 16777216  : 25,165,824
  //   WcT    @ 41943040  :  8,388,608
  //   Qb     @ 50331648  : 16,777,216
  //   Kb     @ 67108864  : 16,777,216
  //   VTb    @ 83886080  : 16,777,216   -> total 100,663,296 B
  if (ws_size < 100663296u) return;
  char* w = (char*)d_ws;
  bf16* x16   = (bf16*)(w);
  bf16* WqkvT = (bf16*)(w + (size_t)16777216);
  bf16* WcT   = (bf16*)(w + (size_t)41943040);
  bf16* Qb    = (bf16*)(w + (size_t)50331648);
  bf16* Kb    = (bf16*)(w + (size_t)67108864);
  bf16* VTb   = (bf16*)(w + (size_t)83886080);
  bf16* attnA = x16;   // overlay: x16 dead after GEMM1

  // allow dynamic LDS (idempotent; not a stream op -> capture-safe)
  hipFuncSetAttribute(reinterpret_cast<const void*>(&k_gemmP<1>),
                      hipFuncAttributeMaxDynamicSharedMemorySize, 49152);
  hipFuncSetAttribute(reinterpret_cast<const void*>(&k_gemmP<2>),
                      hipFuncAttributeMaxDynamicSharedMemorySize, 49152);
  hipFuncSetAttribute(reinterpret_cast<const void*>(&k_attn),
                      hipFuncAttributeMaxDynamicSharedMemorySize, 73728);

  k_cvt<<<(MTOT*MODEL/4 + 255)/256, 256, 0, stream>>>(x, x16, MTOT*MODEL/4);
  k_transpose<<<dim3(N1/32,    MODEL/32), 256, 0, stream>>>(Wqkv, WqkvT, MODEL, N1);
  k_transpose<<<dim3(MODEL/32, MODEL/32), 256, 0, stream>>>(Wc,   WcT,   MODEL, MODEL);

  // grid 48*32 = 1536 blocks (3 blocks/CU -> 2 exact rounds of 768)
  k_gemmP<1><<<(N1/128)*(MTOT/128), 512, 49152, stream>>>(
      x16, WqkvT, MTOT, N1, MODEL,
      nullptr, nullptr, Qb, Kb, VTb, cosT, sinT);

  // grid 8*32 = 256 blocks, 8 waves each, paired q-tiles share staged KV
  k_attn<<<dim3(8, BB*NHEAD), 512, 73728, stream>>>(Qb, Kb, VTb, attnA);

  // grid 16*32 = 512 blocks
  k_gemmP<2><<<(MODEL/128)*(MTOT/128), 512, 49152, stream>>>(
      attnA, WcT, MTOT, MODEL, MODEL,
      out, bc, nullptr, nullptr, nullptr, nullptr, nullptr);
}